// Round 20
// 269.538 us; speedup vs baseline: 1.2813x; 1.1044x over previous
//
#include <hip/hip_runtime.h>
#include <hip/hip_bf16.h>
#include <cstdint>
#include <cstddef>

// ---------- types & helpers ----------
typedef __attribute__((ext_vector_type(8))) short short8;   // 8 x bf16
typedef __attribute__((ext_vector_type(4))) short short4v;  // 4 x bf16 (8B)
typedef __attribute__((ext_vector_type(4))) float f32x4;

#define DEVINL static __device__ __forceinline__

DEVINL float b2f(unsigned short u) {
    union { unsigned int i; float f; } v; v.i = ((unsigned int)u) << 16; return v.f;
}
// hardware cvt (single-instr bf16 convert, RNE)
DEVINL unsigned short f2bh(float f) {
    __hip_bfloat16 h = __float2bfloat16(f);
    union { __hip_bfloat16 h; unsigned short u; } v; v.h = h; return v.u;
}
// f2b delegates to the hardware convert (identical RNE semantics)
DEVINL unsigned short f2b(float f) { return f2bh(f); }
// short8 (8 bf16) -> two f32x4
DEVINL void cv8(short8 h, f32x4& lo, f32x4& hi) {
    #pragma unroll
    for (int j = 0; j < 4; ++j) {
        lo[j] = b2f((unsigned short)h[j]);
        hi[j] = b2f((unsigned short)h[j + 4]);
    }
}
// short4v (4 bf16) -> f32x4
DEVINL void cv4(short4v h, f32x4& o) {
    #pragma unroll
    for (int j = 0; j < 4; ++j) o[j] = b2f((unsigned short)h[j]);
}
// async global->LDS, 16B per lane; LDS dest is wave-uniform base + lane*16
DEVINL void stage16(const unsigned short* g, unsigned short* l) {
    __builtin_amdgcn_global_load_lds(
        (const __attribute__((address_space(1))) unsigned int*)g,
        (__attribute__((address_space(3))) unsigned int*)l,
        16, 0, 0);
}
// XCD-aware swizzle, bx-ownership: XCD k (id%8) owns bx in [4k,4k+4), all by.
// Per-XCD working set = 4 A-panels (1MB) + full B (2MB) -> fits 4MB L2.
// Bijective on 256 ids: k=id&7 (disjoint bx ranges), m=id>>3 covers 4x8 tiles.
DEVINL void xcd_swz(int& bx, int& by) {
    int id = by * 32 + bx;
    int k = id & 7, m = id >> 3;
    bx = 4 * k + (m & 3);
    by = m >> 2;
}

static constexpr int Bsz = 4, Tn = 1024, Cn = 1024, Hn = 16, Nn = 64;
static constexpr int Mrows = Bsz * Tn;             // 4096
static constexpr size_t MX = (size_t)Mrows * Cn;   // 4,194,304
static constexpr int NCHUNK = 16, CL = 64;         // 16 chunks x 64 steps
static constexpr int DLD = 65;                     // padded Dl stride (bank spread)

// ---------- fused prep: token-shift premix + big-weight cvt + small transposes ----------
__global__ __launch_bounds__(256) void k_prep_all(
    const float* __restrict__ x,
    const float* __restrict__ mr, const float* __restrict__ mw,
    const float* __restrict__ mk, const float* __restrict__ mv,
    const float* __restrict__ ma, const float* __restrict__ mg,
    unsigned short* __restrict__ xr, unsigned short* __restrict__ xw,
    unsigned short* __restrict__ xk, unsigned short* __restrict__ xv,
    unsigned short* __restrict__ xa, unsigned short* __restrict__ xg,
    const float* __restrict__ Wr, const float* __restrict__ Wk,
    const float* __restrict__ Wv, const float* __restrict__ Wo,
    unsigned short* __restrict__ WrB, unsigned short* __restrict__ WkB,
    unsigned short* __restrict__ WvB, unsigned short* __restrict__ WoB,
    const float* __restrict__ w1, const float* __restrict__ w2,
    const float* __restrict__ a1, const float* __restrict__ a2,
    const float* __restrict__ v1, const float* __restrict__ v2,
    const float* __restrict__ g1, const float* __restrict__ g2,
    unsigned short* __restrict__ w1T, unsigned short* __restrict__ w2T,
    unsigned short* __restrict__ a1T, unsigned short* __restrict__ a2T,
    unsigned short* __restrict__ v1T, unsigned short* __restrict__ v2T,
    unsigned short* __restrict__ g1T, unsigned short* __restrict__ g2T)
{
    const int bx = blockIdx.x;
    const int tid = threadIdx.x;
    if (bx < 2048) {
        size_t e = ((size_t)bx * 256 + tid) * 8;
        int c = (int)(e & (Cn - 1));
        int t = (int)((e >> 10) & (Tn - 1));
        float xf[8], d[8];
        {
            f32x4 x0 = *(const f32x4*)(x + e);
            f32x4 x1 = *(const f32x4*)(x + e + 4);
            #pragma unroll
            for (int j = 0; j < 4; ++j) { xf[j] = x0[j]; xf[4 + j] = x1[j]; }
        }
        if (t > 0) {
            f32x4 p0 = *(const f32x4*)(x + e - Cn);
            f32x4 p1 = *(const f32x4*)(x + e - Cn + 4);
            #pragma unroll
            for (int j = 0; j < 4; ++j) { d[j] = p0[j] - xf[j]; d[4 + j] = p1[j] - xf[4 + j]; }
        } else {
            #pragma unroll
            for (int j = 0; j < 8; ++j) d[j] = -xf[j];
        }
        const float* ms[6] = { mr, mw, mk, mv, ma, mg };
        unsigned short* ds[6] = { xr, xw, xk, xv, xa, xg };
        #pragma unroll
        for (int p = 0; p < 6; ++p) {
            f32x4 m0 = *(const f32x4*)(ms[p] + c);
            f32x4 m1 = *(const f32x4*)(ms[p] + c + 4);
            short8 o;
            #pragma unroll
            for (int j = 0; j < 4; ++j) {
                o[j]     = (short)f2b(xf[j]     + d[j]     * m0[j]);
                o[4 + j] = (short)f2b(xf[4 + j] + d[4 + j] * m1[j]);
            }
            *(short8*)(ds[p] + e) = o;
        }
    } else if (bx < 6144) {
        int b2 = bx - 2048;
        int sel = b2 >> 10;
        const float* in = (sel == 0) ? Wr : (sel == 1) ? Wk : (sel == 2) ? Wv : Wo;
        unsigned short* out = (sel == 0) ? WrB : (sel == 1) ? WkB : (sel == 2) ? WvB : WoB;
        int i = (((b2 & 1023) << 8) + tid) * 4;
        f32x4 v = *(const f32x4*)(in + i);
        short4v o;
        #pragma unroll
        for (int j = 0; j < 4; ++j) o[j] = (short)f2b(v[j]);
        *(short4v*)(out + i) = o;
    } else {
        int idx = (bx - 6144) * 256 + tid;
        if (idx < 65536) {
            int r = idx >> 6, c = idx & 63;
            w1T[c * 1024 + r] = f2b(w1[idx]);
        } else if (idx < 131072) {
            int j = idx - 65536; int r = j >> 10, c = j & 1023;
            w2T[c * 64 + r] = f2b(w2[j]);
        } else if (idx < 196608) {
            int j = idx - 131072; int r = j >> 6, c = j & 63;
            a1T[c * 1024 + r] = f2b(a1[j]);
        } else if (idx < 262144) {
            int j = idx - 196608; int r = j >> 10, c = j & 1023;
            a2T[c * 64 + r] = f2b(a2[j]);
        } else if (idx < 327680) {
            int j = idx - 262144; int r = j >> 6, c = j & 63;
            v1T[c * 1024 + r] = f2b(v1[j]);
        } else if (idx < 393216) {
            int j = idx - 327680; int r = j >> 10, c = j & 1023;
            v2T[c * 64 + r] = f2b(v2[j]);
        } else if (idx < 557056) {
            int j = idx - 393216; int r = j / 160, c = j - r * 160;
            g1T[c * 1024 + r] = f2b(g1[j]);
        } else if (idx < 720896) {
            int j = idx - 557056; int r = j >> 10, c = j & 1023;
            g2T[c * 160 + r] = f2b(g2[j]);
        }
    }
}

// epi: 0=raw 1=tanh 2=sigmoid 3=bias+sigmoid 4=bias+decay
template<int EPI, int OUTF32>
DEVINL void gemm_epi(f32x4 (&acc)[4][4], int m0, int n0, int N, int ldc,
                     float* Cf, unsigned short* Cb, const float* bias, int lane)
{
    int r16 = lane & 15;
    #pragma unroll
    for (int mi = 0; mi < 4; ++mi)
        #pragma unroll
        for (int ni = 0; ni < 4; ++ni) {
            int col = n0 + ni * 16 + r16;
            if (col < N) {
                float bv = (EPI >= 3) ? bias[col] : 0.f;
                #pragma unroll
                for (int r = 0; r < 4; ++r) {
                    int row = m0 + mi * 16 + (lane >> 4) * 4 + r;
                    float v = acc[mi][ni][r];
                    if (EPI == 1) v = tanhf(v);
                    else if (EPI == 2) v = 1.f / (1.f + expf(-v));
                    else if (EPI == 3) { v += bv; v = 1.f / (1.f + expf(-v)); }
                    else if (EPI == 4) { v += bv; v = expf(-0.60653066f / (1.f + expf(-v))); }
                    size_t o = (size_t)row * ldc + col;
                    if (OUTF32) Cf[o] = v; else Cb[o] = f2b(v);
                }
            }
        }
}

// ---------- LDS-staged GEMM body: 128x128 tile, BK=32, double-buffered ----------
template<int EPI, int OUTF32>
DEVINL void gemm_lds_body(const unsigned short* __restrict__ A, int lda,
                          const unsigned short* __restrict__ Bt, int ldb,
                          float* __restrict__ Cf, unsigned short* __restrict__ Cb,
                          int ldc, const float* __restrict__ bias, int K,
                          int m0, int n0)
{
    __shared__ unsigned short As[2][128 * 32];
    __shared__ unsigned short Bs[2][128 * 32];
    const int tid = threadIdx.x, wid = tid >> 6, lane = tid & 63;
    const int r16 = lane & 15, kg = lane >> 4;
    const int wr = (wid >> 1) * 64, wc = (wid & 1) * 64;

    const int srow = wid * 32 + (lane >> 2);
    const int scol = (lane & 3) * 8;
    const int lbase = wid * 1024 + lane * 8;
    const unsigned short* aS = A + (size_t)(m0 + srow) * lda + scol;
    const unsigned short* bS = Bt + (size_t)(n0 + srow) * ldb + scol;

    f32x4 acc[4][4];
    #pragma unroll
    for (int a = 0; a < 4; ++a)
        #pragma unroll
        for (int b = 0; b < 4; ++b) acc[a][b] = (f32x4){0.f, 0.f, 0.f, 0.f};

    const int nk = K >> 5;
    stage16(aS, &As[0][lbase]);
    stage16(aS + (size_t)16 * lda, &As[0][lbase + 512]);
    stage16(bS, &Bs[0][lbase]);
    stage16(bS + (size_t)16 * ldb, &Bs[0][lbase + 512]);
    __syncthreads();

    for (int kk = 0; kk < nk; ++kk) {
        const int buf = kk & 1;
        if (kk + 1 < nk) {
            const int k0 = (kk + 1) * 32;
            stage16(aS + k0, &As[buf ^ 1][lbase]);
            stage16(aS + k0 + (size_t)16 * lda, &As[buf ^ 1][lbase + 512]);
            stage16(bS + k0, &Bs[buf ^ 1][lbase]);
            stage16(bS + k0 + (size_t)16 * ldb, &Bs[buf ^ 1][lbase + 512]);
        }
        short8 af[4], bf[4];
        #pragma unroll
        for (int mi = 0; mi < 4; ++mi)
            af[mi] = *(const short8*)&As[buf][(wr + mi * 16 + r16) * 32 + kg * 8];
        #pragma unroll
        for (int ni = 0; ni < 4; ++ni)
            bf[ni] = *(const short8*)&Bs[buf][(wc + ni * 16 + r16) * 32 + kg * 8];
        #pragma unroll
        for (int mi = 0; mi < 4; ++mi)
            #pragma unroll
            for (int ni = 0; ni < 4; ++ni)
                acc[mi][ni] = __builtin_amdgcn_mfma_f32_16x16x32_bf16(af[mi], bf[ni], acc[mi][ni], 0, 0, 0);
        __syncthreads();
    }
    gemm_epi<EPI, OUTF32>(acc, m0 + wr, n0 + wc, 1 << 30, ldc, Cf, Cb, bias, lane);
}

// ---------- direct-global MFMA core (tall-skinny stage-1) ----------
DEVINL void gemm_core(const unsigned short* __restrict__ A, int lda,
                      const unsigned short* __restrict__ Bt, int ldb,
                      int m0, int n0, int N, int K, int r16, int k8,
                      f32x4 (&acc)[4][4])
{
    for (int k0 = 0; k0 < K; k0 += 32) {
        short8 af[4], bf[4];
        #pragma unroll
        for (int mi = 0; mi < 4; ++mi)
            af[mi] = *(const short8*)(A + (size_t)(m0 + mi * 16 + r16) * lda + k0 + k8);
        #pragma unroll
        for (int ni = 0; ni < 4; ++ni) {
            int rn = n0 + ni * 16 + r16;
            if (rn >= N) rn = N - 1;
            bf[ni] = *(const short8*)(Bt + (size_t)rn * ldb + k0 + k8);
        }
        #pragma unroll
        for (int mi = 0; mi < 4; ++mi)
            #pragma unroll
            for (int ni = 0; ni < 4; ++ni)
                acc[mi][ni] = __builtin_amdgcn_mfma_f32_16x16x32_bf16(af[mi], bf[ni], acc[mi][ni], 0, 0, 0);
    }
}

// ---------- MERGED front GEMMs, COMPACT 1D grid (864 blocks):
//   b 0..95   : four tall-skinny stage-1 GEMMs (dispatched FIRST, co-resident)
//   b 96..863 : R/K/V 128x128 LDS-staged GEMMs (256 blocks each, bx-owning swz)
__global__ __launch_bounds__(256) void gemm_front(
    const unsigned short* __restrict__ Ar, const unsigned short* __restrict__ Ak,
    const unsigned short* __restrict__ Avv,
    const unsigned short* __restrict__ Br, const unsigned short* __restrict__ Bk,
    const unsigned short* __restrict__ Bv,
    unsigned short* __restrict__ Dr, unsigned short* __restrict__ Dk,
    unsigned short* __restrict__ Dv,
    const unsigned short* __restrict__ Aw, const unsigned short* __restrict__ Aa,
    const unsigned short* __restrict__ Ag,
    const unsigned short* __restrict__ Bw1, const unsigned short* __restrict__ Ba1,
    const unsigned short* __restrict__ Bv1, const unsigned short* __restrict__ Bg1,
    unsigned short* __restrict__ Dw, unsigned short* __restrict__ Da,
    unsigned short* __restrict__ Dvh, unsigned short* __restrict__ Dg)
{
    const int b = blockIdx.x;
    if (b >= 96) {
        const int lb = b - 96;
        const int z = lb >> 8;
        int bxs = lb & 31, bys = (lb >> 5) & 7;
        xcd_swz(bxs, bys);
        const unsigned short* A = (z == 0) ? Ar : (z == 1) ? Ak : Avv;
        const unsigned short* Bt = (z == 0) ? Br : (z == 1) ? Bk : Bv;
        unsigned short* D = (z == 0) ? Dr : (z == 1) ? Dk : Dv;
        gemm_lds_body<0, 0>(A, Cn, Bt, Cn, nullptr, D, Cn, nullptr, Cn,
                            bxs * 128, bys * 128);
        return;
    }
    int zz, bxi, byi;
    if (b < 48) { zz = b >> 4; bxi = b & 15; byi = 0; }
    else        { zz = 3; int r = b - 48; bxi = r & 15; byi = r >> 4; }
    const unsigned short* A = (zz == 0) ? Aw : (zz == 1) ? Aa : (zz == 2) ? Avv : Ag;
    const unsigned short* Bt = (zz == 0) ? Bw1 : (zz == 1) ? Ba1 : (zz == 2) ? Bv1 : Bg1;
    const int N = (zz == 3) ? 160 : 64;
    const int tid = threadIdx.x, wid = tid >> 6, lane = tid & 63;
    const int r16 = lane & 15, k8 = (lane >> 4) * 8;
    const int m0 = bxi * 256 + wid * 64;
    const int n0 = byi * 64;
    f32x4 acc[4][4];
    #pragma unroll
    for (int a = 0; a < 4; ++a)
        #pragma unroll
        for (int bb = 0; bb < 4; ++bb) acc[a][bb] = (f32x4){0.f, 0.f, 0.f, 0.f};
    gemm_core(A, Cn, Bt, Cn, m0, n0, N, Cn, r16, k8, acc);
    if (zz == 0)      gemm_epi<1, 0>(acc, m0, n0, N, 64,  nullptr, Dw, nullptr, lane);
    else if (zz == 1) gemm_epi<0, 0>(acc, m0, n0, N, 64,  nullptr, Da, nullptr, lane);
    else if (zz == 2) gemm_epi<0, 0>(acc, m0, n0, N, 64,  nullptr, Dvh, nullptr, lane);
    else              gemm_epi<2, 0>(acc, m0, n0, N, 160, nullptr, Dg, nullptr, lane);
}

// ---------- the four stage-2 GEMMs in ONE launch (bx-owning XCD swizzle) ----------
__global__ __launch_bounds__(256) void gemm_s2(
    const unsigned short* __restrict__ hw, const unsigned short* __restrict__ ha,
    const unsigned short* __restrict__ hv, const unsigned short* __restrict__ hg,
    const unsigned short* __restrict__ w2T, const unsigned short* __restrict__ a2T,
    const unsigned short* __restrict__ v2T, const unsigned short* __restrict__ g2T,
    float* __restrict__ Wdec, unsigned short* __restrict__ Ab,
    unsigned short* __restrict__ SVb, unsigned short* __restrict__ Gb,
    const float* __restrict__ w0, const float* __restrict__ a0,
    const float* __restrict__ v0)
{
    const int z = blockIdx.z;
    int bxs = blockIdx.x, bys = blockIdx.y;
    xcd_swz(bxs, bys);
    const int m0 = bxs * 128, n0 = bys * 128;
    if (z == 0)
        gemm_lds_body<4, 1>(hw, 64, w2T, 64, Wdec, nullptr, Cn, w0, 64, m0, n0);
    else if (z == 1)
        gemm_lds_body<3, 0>(ha, 64, a2T, 64, nullptr, Ab, Cn, a0, 64, m0, n0);
    else if (z == 2)
        gemm_lds_body<3, 0>(hv, 64, v2T, 64, nullptr, SVb, Cn, v0, 64, m0, n0);
    else
        gemm_lds_body<0, 0>(hg, 160, g2T, 160, nullptr, Gb, Cn, nullptr, 160, m0, n0);
}

// ================= chunked scan (WY form) =================
// kA_wy (1024 thr, 16 waves): per (chain, chunk).
__global__ __launch_bounds__(1024, 1) void kA_wy(
    const float* __restrict__ Wp,
    unsigned short* __restrict__ Kp,        // raw k -> k_final (in place)
    unsigned short* __restrict__ Vp,        // raw v -> v_final (in place)
    const unsigned short* __restrict__ SVp, // sigmoid(v-gate)
    unsigned short* __restrict__ Aap,       // sigmoid(a) -> bb (in place)
    const float* __restrict__ vfirst,
    const float* __restrict__ kkw, const float* __restrict__ kaw,
    float* __restrict__ Pg,                 // stores P^T
    float* __restrict__ Cg,                 // C[i][j]
    float* __restrict__ Qg,                 // Q[t][j']
    float* __restrict__ SAp)                // sa0 (strided)
{
    __shared__ float Dl[64 * DLD];           // cumulative decay (padded)
    __shared__ float Lf[64 * 72];            // L f32; later SA0T h/l (shorts)
    __shared__ float Xf[64 * 132];           // solve buffer [Q | SA0]
    __shared__ unsigned short ah[64 * 72], al[64 * 72];   // ahat h/l -> QT h/l
    __shared__ unsigned short bh_[64 * 72], bl_[64 * 72]; // bhat h/l -> BhatT h/l
    __shared__ unsigned short kh[64 * 72], kl[64 * 72];   // khat h/l -> KhatT h/l
    __shared__ unsigned short vt[64 * 72];                // V^T
    __shared__ unsigned short sc[64 * 72];                // temp V rows -> Lk scores
    __shared__ float dT[64];

    const int tid = threadIdx.x;
    const int bx = blockIdx.x;
    const int bhd = bx >> 4, cc = bx & 15;
    const size_t base0 = ((size_t)(bhd >> 4) * Tn + (size_t)cc * CL) * Cn + (size_t)(bhd & 15) * Nn;
    const size_t mb = (size_t)bx * 4096;

    // ---- P0: staging + fused elementwise-1 (V rows -> sc temp, row-major) ----
    {
        const int t = tid >> 4, s4 = (tid & 15) * 4;
        const size_t g = base0 + (size_t)t * Cn + s4;
        const int ch = (bhd & 15) * Nn + s4;

        f32x4 kv, av, vv, sv;
        cv4(*(const short4v*)(Kp + g), kv);
        cv4(*(const short4v*)(Aap + g), av);
        cv4(*(const short4v*)(Vp + g), vv);
        cv4(*(const short4v*)(SVp + g), sv);
        f32x4 kkwv = *(const f32x4*)(kkw + ch);
        f32x4 kawv = *(const f32x4*)(kaw + ch);
        f32x4 vfv  = *(const f32x4*)(vfirst + g);

        f32x4 kkv = kv * kkwv;
        f32x4 sq = kkv * kkv;
        float s = sq[0] + sq[1] + sq[2] + sq[3];
        s += __shfl_xor(s, 1, 64); s += __shfl_xor(s, 2, 64);
        s += __shfl_xor(s, 4, 64); s += __shfl_xor(s, 8, 64);
        float inv = 1.f / fmaxf(sqrtf(s), 1e-12f);

        short4v o_a, o_b, o_k, o_v;
        #pragma unroll
        for (int j = 0; j < 4; ++j) {
            float kkx = kkv[j] * inv;
            o_a[j] = (short)f2b(-kkx);
            o_b[j] = (short)f2b(kkx * av[j]);
            float kf = kv[j] * (1.f + (av[j] - 1.f) * kawv[j]);
            o_k[j] = (short)f2b(kf);
            float vf = vv[j] + (vfv[j] - vv[j]) * sv[j];
            o_v[j] = (short)f2b(vf);
        }
        *(short4v*)&ah[t * 72 + s4] = o_a;        // raw aa
        *(short4v*)&bh_[t * 72 + s4] = o_b;       // raw bb
        *(short4v*)&kh[t * 72 + s4] = o_k;        // k_final
        *(short4v*)&sc[t * 72 + s4] = o_v;        // V rows (temp)
        *(short4v*)(Kp + g) = o_k;
        *(short4v*)(Vp + g) = o_v;
        *(short4v*)(Aap + g) = o_b;
    }
    __syncthreads();

    // ---- P1: cumulative decay (16 segments x 4 rows, padded stride) ----
    float wreg[4];
    {
        const int j = tid & 63, seg = tid >> 6;   // seg 0..15
        const float* wp = Wp + base0 + (size_t)(seg * 4) * Cn + j;
        float run = 1.f;
        #pragma unroll
        for (int u = 0; u < 4; ++u) { wreg[u] = wp[(size_t)u * Cn]; run *= wreg[u]; }
        Xf[seg * 64 + j] = run;
    }
    __syncthreads();
    {
        const int j = tid & 63, seg = tid >> 6;
        float d = 1.f;
        for (int q = 0; q < seg; ++q) d *= Xf[q * 64 + j];
        #pragma unroll
        for (int u = 0; u < 4; ++u) { d *= wreg[u]; Dl[(seg * 4 + u) * DLD + j] = d; }
        if (seg == 15) dT[j] = d;
    }
    __syncthreads();

    // ---- P2: scaled operands (vectorized short4 row ops, in place, hi/lo) ----
    {
        const int t = tid >> 4, s4 = (tid & 15) * 4;
        short4v a4 = *(const short4v*)&ah[t * 72 + s4];
        short4v b4 = *(const short4v*)&bh_[t * 72 + s4];
        short4v k4 = *(const short4v*)&kh[t * 72 + s4];
        short4v oah, oal, obh, obl, okh, okl;
        #pragma unroll
        for (int jj = 0; jj < 4; ++jj) {
            const int j = s4 + jj;
            const float Dt = Dl[t * DLD + j];
            const float Dp = (t == 0) ? 1.f : Dl[(t - 1) * DLD + j];
            const float inv = __builtin_amdgcn_rcpf(Dt);
            float av = b2f((unsigned short)a4[jj]) * Dp;
            unsigned short h = f2bh(av);
            oah[jj] = (short)h; oal[jj] = (short)f2bh(av - b2f(h));
            float bv = b2f((unsigned short)b4[jj]) * inv;
            h = f2bh(bv);
            obh[jj] = (short)h; obl[jj] = (short)f2bh(bv - b2f(h));
            float kv = b2f((unsigned short)k4[jj]) * inv;
            h = f2bh(kv);
            okh[jj] = (short)h; okl[jj] = (short)f2bh(kv - b2f(h));
        }
        *(short4v*)&ah[t * 72 + s4] = oah;  *(short4v*)&al[t * 72 + s4] = oal;
        *(short4v*)&bh_[t * 72 + s4] = obh; *(short4v*)&bl_[t * 72 + s4] = obl;
        *(short4v*)&kh[t * 72 + s4] = okh;  *(short4v*)&kl[t * 72 + s4] = okl;
    }
    {   // V^T: column reads of sc (broadcast-friendly) + short4 row writes
        const int rj = tid & 63, tq = tid >> 6;   // tq 0..15
        short4v ov;
        #pragma unroll
        for (int u = 0; u < 4; ++u)
            ov[u] = (short)sc[(tq * 4 + u) * 72 + rj];
        *(short4v*)&vt[rj * 72 + tq * 4] = ov;
    }
    __syncthreads();

    const int w = tid >> 6, lane = tid & 63;
    const int r16 = lane & 15, kg = lane >> 4;
    const int rt = w >> 2, ct = w & 3;   // one 16x16 tile per wave

    // ---- P3: scores ----
    {
        if (ct > rt) {
            #pragma unroll
            for (int r = 0; r < 4; ++r)
                sc[(rt * 16 + kg * 4 + r) * 72 + ct * 16 + r16] = 0;
        } else {
            short8 Ah[2], Al2[2];
            #pragma unroll
            for (int ks = 0; ks < 2; ++ks) {
                Ah[ks]  = *(const short8*)&ah[(rt * 16 + r16) * 72 + ks * 32 + kg * 8];
                Al2[ks] = *(const short8*)&al[(rt * 16 + r16) * 72 + ks * 32 + kg * 8];
            }
            f32x4 aL = (f32x4){0.f, 0.f, 0.f, 0.f};
            f32x4 aK = (f32x4){0.f, 0.f, 0.f, 0.f};
            #pragma unroll
            for (int ks = 0; ks < 2; ++ks) {
                const int so = (ct * 16 + r16) * 72 + ks * 32 + kg * 8;
                short8 Bh = *(const short8*)&bh_[so];
                short8 Bl = *(const short8*)&bl_[so];
                aL = __builtin_amdgcn_mfma_f32_16x16x32_bf16(Ah[ks], Bh, aL, 0, 0, 0);
                aL = __builtin_amdgcn_mfma_f32_16x16x32_bf16(Ah[ks], Bl, aL, 0, 0, 0);
                aL = __builtin_amdgcn_mfma_f32_16x16x32_bf16(Al2[ks], Bh, aL, 0, 0, 0);
                short8 Kh2 = *(const short8*)&kh[so];
                short8 Kl2 = *(const short8*)&kl[so];
                aK = __builtin_amdgcn_mfma_f32_16x16x32_bf16(Ah[ks], Kh2, aK, 0, 0, 0);
                aK = __builtin_amdgcn_mfma_f32_16x16x32_bf16(Ah[ks], Kl2, aK, 0, 0, 0);
                aK = __builtin_amdgcn_mfma_f32_16x16x32_bf16(Al2[ks], Kh2, aK, 0, 0, 0);
            }
            #pragma unroll
            for (int r = 0; r < 4; ++r) {
                const int t = rt * 16 + kg * 4 + r;
                const int s = ct * 16 + r16;
                Lf[t * 72 + s] = (s < t) ? aL[r] : 0.f;
                sc[t * 72 + s] = (s < t) ? f2bh(aK[r]) : (unsigned short)0;
            }
        }
    }
    __syncthreads();

    // ---- P4: RHS [Ahat | Lk V^T] ----
    {
        const int t = tid >> 4, s4 = (tid & 15) * 4;
        #pragma unroll
        for (int jj = 0; jj < 4; ++jj)
            Xf[t * 132 + s4 + jj] = b2f(ah[t * 72 + s4 + jj]) + b2f(al[t * 72 + s4 + jj]);
    }
    {
        f32x4 acc = (f32x4){0.f, 0.f, 0.f, 0.f};
        #pragma unroll
        for (int ks = 0; ks < 2; ++ks) {
            short8 Af = *(const short8*)&sc[(rt * 16 + r16) * 72 + ks * 32 + kg * 8];
            short8 Bf = *(const short8*)&vt[(ct * 16 + r16) * 72 + ks * 32 + kg * 8];
            acc = __builtin_amdgcn_mfma_f32_16x16x32_bf16(Af, Bf, acc, 0, 0, 0);
        }
        #pragma unroll
        for (int r = 0; r < 4; ++r)
            Xf[(rt * 16 + kg * 4 + r) * 132 + 64 + ct * 16 + r16] = acc[r];
    }
    __syncthreads();

    // ---- P5: blocked forward substitution (off-diag: 2 rows/thread, s-outer) ----
    for (int bi = 0; bi < 4; ++bi) {
        if (bi > 0) {
            const int c = tid & 127;
            const int rb = tid >> 7;            // 0..7
            const int t0 = bi * 16 + rb * 2;
            float a0 = Xf[t0 * 132 + c];
            float a1 = Xf[(t0 + 1) * 132 + c];
            for (int s = 0; s < bi * 16; ++s) {
                float xv = Xf[s * 132 + c];
                a0 += Lf[t0 * 72 + s] * xv;
                a1 += Lf[(t0 + 1) * 72 + s] * xv;
            }
            Xf[t0 * 132 + c] = a0;
            Xf[(t0 + 1) * 132 + c] = a1;
            __syncthreads();
        }
        if (w < 2) {
            const int c = w * 64 + lane;
            float xcol[16];
            #pragma unroll
            for (int u = 0; u < 16; ++u) xcol[u] = Xf[(bi * 16 + u) * 132 + c];
            for (int rr = 1; rr < 16; ++rr) {
                float a2 = xcol[rr];
                for (int s = 0; s < rr; ++s)
                    a2 += Lf[(bi * 16 + rr) * 72 + bi * 16 + s] * xcol[s];
                xcol[rr] = a2;
            }
            #pragma unroll
            for (int u = 1; u < 16; ++u) Xf[(bi * 16 + u) * 132 + c] = xcol[u];
        }
        __syncthreads();
    }

    // ---- P6: outputs + transposes via column-read / row-write ----
    {
        const int rj = tid & 63, tq = tid >> 6;   // tq 0..15
        float qv[4], sv[4];
        unsigned short bhv[4], blv[4], khv[4], klv[4];
        #pragma unroll
        for (int u = 0; u < 4; ++u) {
            const int t = tq * 4 + u;
            qv[u] = Xf[t * 132 + rj];
            sv[u] = Xf[t * 132 + 64 + rj];
            bhv[u] = bh_[t * 72 + rj];
            blv[u] = bl_[t * 72 + rj];
            khv[u] = kh[t * 72 + rj];
            klv[u] = kl[t * 72 + rj];
        }
        // global writes (lane-coalesced over rj)
        #pragma unroll
        for (int u = 0; u < 4; ++u) {
            const int t = tq * 4 + u;
            Qg[mb + (size_t)t * 64 + rj] = qv[u];
            SAp[base0 + (size_t)t * Cn + rj] = sv[u];
        }
        __syncthreads();   // all column reads done before row overwrites
        unsigned short* sath = (unsigned short*)Lf;
        unsigned short* satl = ((unsigned short*)Lf) + 64 * 72;
        short4v oqh, oql, osh, osl, obh, obl, okh, okl;
        #pragma unroll
        for (int u = 0; u < 4; ++u) {
            unsigned short h = f2bh(qv[u]);
            oqh[u] = (short)h; oql[u] = (short)f2bh(qv[u] - b2f(h));
            h = f2bh(sv[u]);
            osh[u] = (short)h; osl[u] = (short)f2bh(sv[u] - b2f(h));
            obh[u] = (short)bhv[u]; obl[u] = (short)blv[u];
            okh[u] = (short)khv[u]; okl[u] = (short)klv[u];
        }
        *(short4v*)&ah[rj * 72 + tq * 4] = oqh;
        *(short4v*)&al[rj * 72 + tq * 4] = oql;
        *(short4v*)&sath[rj * 72 + tq * 4] = osh;
        *(short4v*)&satl[rj * 72 + tq * 4] = osl;
        *(short4v*)&bh_[rj * 72 + tq * 4] = obh;
        *(short4v*)&bl_[rj * 72 + tq * 4] = obl;
        *(short4v*)&kh[rj * 72 + tq * 4] = okh;
        *(short4v*)&kl[rj * 72 + tq * 4] = okl;
    }
    __syncthreads();

    // ---- P7: epilogue P^T and C via MFMA (one tile per wave) ----
    {
        unsigned short* sath = (unsigned short*)Lf;
        unsigned short* satl = ((unsigned short*)Lf) + 64 * 72;
        f32x4 aP = (f32x4){0.f, 0.f, 0.f, 0.f};
        f32x4 aC = (f32x4){0.f, 0.f, 0.f, 0.f};
        #pragma unroll
        for (int ks = 0; ks < 2; ++ks) {
            const int ro = (rt * 16 + r16) * 72 + ks * 32 + kg * 8;
            const int co = (ct * 16 + r16) * 72 + ks * 32 + kg * 8;
            short8 Abh = *(const short8*)&bh_[ro];
            short8 Abl = *(const short8*)&bl_[ro];
            short8 Bqh = *(const short8*)&ah[co];
            short8 Bql = *(const short8*)&al[co];
            aP = __builtin_amdgcn_mfma_f32_16x16x32_bf16(Abh, Bqh, aP, 0, 0, 0);
            aP = __builtin_amdgcn_mfma_f32_16x16x32_bf16(Abh, Bql, aP, 0, 0, 0);
            aP = __builtin_amdgcn_mfma_f32_16x16x32_bf16(Abl, Bqh, aP, 0, 0, 0);
            short8 Ash = *(const short8*)&sath[ro];
            short8 Asl = *(const short8*)&satl[ro];
            short8 Bbh = *(const short8*)&bh_[co];
            short8 Bbl = *(const short8*)&bl_[co];
            aC = __builtin_amdgcn_mfma_f32_16x16x32_bf16(Ash, Bbh, aC, 0, 0, 0);
            aC = __builtin_amdgcn_mfma_f32_16x16x32_bf16(Ash, Bbl, aC, 0, 0, 0);
            aC = __builtin_amdgcn_mfma_f32_16x16x32_bf16(Asl, Bbh, aC, 0, 0, 0);
            short8 Avt = *(const short8*)&vt[ro];
            short8 Bkh = *(const short8*)&kh[co];
            short8 Bkl = *(const short8*)&kl[co];
            aC = __builtin_amdgcn_mfma_f32_16x16x32_bf16(Avt, Bkh, aC, 0, 0, 0);
            aC = __builtin_amdgcn_mfma_f32_16x16x32_bf16(Avt, Bkl, aC, 0, 0, 0);
        }
        #pragma unroll
        for (int r = 0; r < 4; ++r) {
            const int row = rt * 16 + kg * 4 + r;
            const int col = ct * 16 + r16;
            Pg[mb + (size_t)row * 64 + col] = dT[row] * (aP[r] + ((row == col) ? 1.f : 0.f));
            Cg[mb + (size_t)row * 64 + col] = dT[col] * aC[r];
        }
    }
}

// Phase B (MFMA): sequential chunk combine S <- S*P_c + C_c via matrix pipe.
__global__ __launch_bounds__(256, 1) void kB_combine(
    const float* __restrict__ Pg, const float* __restrict__ Cg,
    float* __restrict__ Sinit)
{
    __shared__ float Sl[64 * 65];
    __shared__ float PT[64 * 65];
    const int tid = threadIdx.x;
    const int w = tid >> 6;
    const int l = tid & 63;
    const int lr = l & 15;
    const int lg = l >> 4;
    const int bh = blockIdx.x;

    f32x4 acc[4];
    #pragma unroll
    for (int t = 0; t < 4; ++t) acc[t] = (f32x4){0.f, 0.f, 0.f, 0.f};

    f32x4 pr[4]; f32x4 cr[4];
    {
        const size_t ob = (size_t)(bh * 16) * 4096;
        #pragma unroll
        for (int u = 0; u < 4; ++u)
            pr[u] = *(const f32x4*)(Pg + ob + (size_t)tid * 16 + u * 4);
        #pragma unroll
        for (int t = 0; t < 4; ++t)
            #pragma unroll
            for (int r = 0; r < 4; ++r)
                cr[t][r] = Cg[ob + (size_t)(16 * w + 4 * lg + r) * 64 + 16 * t + lr];
    }

    for (int c = 0; c < NCHUNK; ++c) {
        const size_t ob = (size_t)(bh * 16 + c) * 4096;
        #pragma unroll
        for (int t = 0; t < 4; ++t)
            #pragma unroll
            for (int r = 0; r < 4; ++r)
                Sinit[ob + (size_t)(16 * w + 4 * lg + r) * 64 + 16 * t + lr] = acc[t][r];
        if (c == NCHUNK - 1) break;

        #pragma unroll
        for (int t = 0; t < 4; ++t)
            #pragma unroll
            for (int r = 0; r < 4; ++r)
                Sl[(16 * w + 4 * lg + r) * 65 + 16 * t + lr] = acc[t][r];
        {
            const int jr = tid >> 2, j0 = (tid & 3) * 16;
            #pragma unroll
            for (int u = 0; u < 4; ++u)
                #pragma unroll
                for (int e = 0; e < 4; ++e)
                    PT[jr * 65 + j0 + u * 4 + e] = pr[u][e];
        }
        __syncthreads();

        f32x4 prn[4] = {}, crn[4] = {};
        if (c + 1 < NCHUNK - 1) {
            const size_t obn = (size_t)(bh * 16 + c + 1) * 4096;
            #pragma unroll
            for (int u = 0; u < 4; ++u)
                prn[u] = *(const f32x4*)(Pg + obn + (size_t)tid * 16 + u * 4);
            #pragma unroll
            for (int t = 0; t < 4; ++t)
                #pragma unroll
                for (int r = 0; r < 4; ++r)
                    crn[t][r] = Cg[obn + (size_t)(16 * w + 4 * lg + r) * 64 + 16 * t + lr];
        }

        short8 ahi[2], alo[2];
        #pragma unroll
        for (int k0 = 0; k0 < 2; ++k0) {
            const float* sp = &Sl[(16 * w + lr) * 65 + k0 * 32 + lg * 8];
            #pragma unroll
            for (int j = 0; j < 8; ++j) {
                float s = sp[j];
                unsigned short h = f2bh(s);
                ahi[k0][j] = (short)h;
                alo[k0][j] = (short)f2bh(s - b2f(h));
            }
        }

        #pragma unroll
        for (int t = 0; t < 4; ++t) {
            f32x4 nacc = cr[t];
            #pragma unroll
            for (int k0 = 0; k0 < 2; ++k0) {
                short8 bhi, blo;
                const float* pp = &PT[(16 * t + lr) * 65 + k0 * 32 + lg * 8];
                #pragma unroll
                for (int j = 0; j < 8; ++j) {
                    float p = pp[j];
                    unsigned short h = f2bh(p);
                    bhi[j] = (short)h;
                    blo[j] = (short)f2bh(p - b2f(h));
                }
                nacc = __builtin_amdgcn_mfma_f32_16x16x32_bf16(ahi[k0], bhi, nacc, 0, 0, 0);
                nacc = __builtin_amdgcn_mfma_f32_16x16x32_bf16(ahi[k0], blo, nacc, 0, 0, 0);
                nacc = __builtin_amdgcn_mfma_f32_16x16x32_bf16(alo[k0], bhi, nacc, 0, 0, 0);
            }
            acc[t] = nacc;
        }
        __syncthreads();
        #pragma unroll
        for (int u = 0; u < 4; ++u) { pr[u] = prn[u]; cr[u] = crn[u]; }
    }
}

// Phase Y (MFMA, WY-form) with kD merged AND k_elem2 FUSED:
//   corr = Q @ S0^T; SA = SA0 + corr -> global + LDS
//   Y = Rhat @ S0^T + tril(Rhat Khat^T) @ V + tril(Rhat Bhat^T) @ SA
//   then per-row groupnorm + bonus + gate -> AG (bf16) directly (no Y in global)
__global__ __launch_bounds__(256) void kY_mfma(
    const float* __restrict__ Wp, const unsigned short* __restrict__ Rp,
    const unsigned short* __restrict__ Kp, const unsigned short* __restrict__ Bbp,
    const unsigned short* __restrict__ Vp, const unsigned short* __restrict__ Gb,
    const float* __restrict__ Qg, const float* __restrict__ Sinit,
    const float* __restrict__ gnw, const float* __restrict__ gnb,
    const float* __restrict__ rk,
    float* __restrict__ SAp,                 // in: sa0; out: corrected
    unsigned short* __restrict__ AG)         // out: (x_att*g) bf16  (== Rp buffer)
{
    __shared__ float Dl[64 * DLD];           // D; later SAf (f32, stride 65) then scoreS
    __shared__ unsigned short khS[64 * 72], klS[64 * 72];
    __shared__ unsigned short bhS[64 * 72], blS[64 * 72];
    __shared__ unsigned short vtS[64 * 72];  // V^T; segP overlay during scan
    __shared__ unsigned short sahS[64 * 72]; // V rows temp -> SA^T (hi)

    unsigned short* scoreS = (unsigned short*)Dl;
    float* SAf = Dl;                          // stride 65 (fits 64*DLD)
    float* segP = (float*)vtS;

    const int tid = threadIdx.x;
    const int bx = blockIdx.x;
    const int bh = bx >> 4, cc = bx & 15;
    const size_t base0 = ((size_t)(bh >> 4) * Tn + (size_t)cc * CL) * Cn + (size_t)(bh & 15) * Nn;
    const size_t mb = (size_t)bx * 4096;

    // ---- D cumprod ----
    float wv[16];
    {
        const int j = tid & 63, seg = tid >> 6;
        float run = 1.f;
        #pragma unroll
        for (int u = 0; u < 16; ++u) {
            wv[u] = Wp[base0 + (size_t)(seg * 16 + u) * Cn + j];
            run *= wv[u];
        }
        segP[seg * 64 + j] = run;
    }
    __syncthreads();
    {
        const int j = tid & 63, seg = tid >> 6;
        float d = 1.f;
        for (int q = 0; q < seg; ++q) d *= segP[q * 64 + j];
        #pragma unroll
        for (int u = 0; u < 16; ++u) {
            d *= wv[u];
            Dl[(seg * 16 + u) * DLD + j] = d;
        }
    }
    __syncthreads();

    const int w = tid >> 6, lane = tid & 63;
    const int r16 = lane & 15, kg = lane >> 4;

    // ---- Rhat A-frags ----
    short8 rh[2], rl[2];
    {
        const int t = 16 * w + r16;
        #pragma unroll
        for (int ks = 0; ks < 2; ++ks) {
            const int j0 = ks * 32 + kg * 8;
            short8 rr = *(const short8*)(Rp + base0 + (size_t)t * Cn + j0);
            const float* dp = &Dl[t * DLD + j0];
            #pragma unroll
            for (int jj = 0; jj < 8; ++jj) {
                float rv = b2f((unsigned short)rr[jj]) * dp[jj];
                unsigned short h = f2bh(rv);
                rh[ks][jj] = (short)h;
                rl[ks][jj] = (short)f2bh(rv - b2f(h));
            }
        }
    }

    // ---- Khat/Bhat rows (vector writes) + V rows into sahS temp ----
    {
        const int s = tid >> 2, j0 = (tid & 3) * 16;
        const size_t g = base0 + (size_t)s * Cn + j0;
        #pragma unroll
        for (int half = 0; half < 2; ++half) {
            short8 kk8 = *(const short8*)(Kp + g + half * 8);
            short8 bb8 = *(const short8*)(Bbp + g + half * 8);
            short8 okh, okl, obh, obl;
            #pragma unroll
            for (int jj = 0; jj < 8; ++jj) {
                float dd = Dl[s * DLD + j0 + half * 8 + jj];
                float inv = __builtin_amdgcn_rcpf(dd);
                float kv = b2f((unsigned short)kk8[jj]) * inv;
                float bv = b2f((unsigned short)bb8[jj]) * inv;
                unsigned short h1 = f2bh(kv);
                okh[jj] = (short)h1; okl[jj] = (short)f2bh(kv - b2f(h1));
                unsigned short h2 = f2bh(bv);
                obh[jj] = (short)h2; obl[jj] = (short)f2bh(bv - b2f(h2));
            }
            *(short8*)&khS[s * 72 + j0 + half * 8] = okh;
            *(short8*)&klS[s * 72 + j0 + half * 8] = okl;
            *(short8*)&bhS[s * 72 + j0 + half * 8] = obh;
            *(short8*)&blS[s * 72 + j0 + half * 8] = obl;
            // V rows (row-major temp)
            *(short8*)&sahS[s * 72 + j0 + half * 8] =
                *(const short8*)(Vp + g + half * 8);
        }
    }
    __syncthreads();

    // ---- V^T: column-read / row-write transpose (sahS temp -> vtS) ----
    {
        const int rj = tid & 63, tq = tid >> 6;   // tq 0..3, 16 rows each
        unsigned short tmp[16];
        #pragma unroll
        for (int u = 0; u < 16; ++u)
            tmp[u] = sahS[(tq * 16 + u) * 72 + rj];
        short8 o0, o1;
        #pragma unroll
        for (int u = 0; u < 8; ++u) { o0[u] = (short)tmp[u]; o1[u] = (short)tmp[8 + u]; }
        *(short8*)&vtS[rj * 72 + tq * 16] = o0;
        *(short8*)&vtS[rj * 72 + tq * 16 + 8] = o1;
    }
    __syncthreads();   // Dl now dead (frags built); SAf region usable

    // ---- Y1 + corr (shared S0 B-frags) ----
    f32x4 acc[4], accC[4];
    #pragma unroll
    for (int ni = 0; ni < 4; ++ni) {
        acc[ni] = (f32x4){0.f, 0.f, 0.f, 0.f};
        accC[ni] = (f32x4){0.f, 0.f, 0.f, 0.f};
    }
    short8 qh[2], ql[2];
    if (cc > 0) {
        const int t = 16 * w + r16;
        #pragma unroll
        for (int ks = 0; ks < 2; ++ks) {
            const int j0 = ks * 32 + kg * 8;
            f32x4 qa = *(const f32x4*)(Qg + mb + (size_t)t * 64 + j0);
            f32x4 qb = *(const f32x4*)(Qg + mb + (size_t)t * 64 + j0 + 4);
            #pragma unroll
            for (int jj = 0; jj < 4; ++jj) {
                unsigned short h1 = f2bh(qa[jj]);
                qh[ks][jj] = (short)h1; ql[ks][jj] = (short)f2bh(qa[jj] - b2f(h1));
                unsigned short h2 = f2bh(qb[jj]);
                qh[ks][4 + jj] = (short)h2; ql[ks][4 + jj] = (short)f2bh(qb[jj] - b2f(h2));
            }
        }
    }
    #pragma unroll
    for (int ni = 0; ni < 4; ++ni) {
        #pragma unroll
        for (int ks = 0; ks < 2; ++ks) {
            const int i = ni * 16 + r16;
            const int j0 = ks * 32 + kg * 8;
            f32x4 s0a = *(const f32x4*)(Sinit + mb + (size_t)i * 64 + j0);
            f32x4 s0b = *(const f32x4*)(Sinit + mb + (size_t)i * 64 + j0 + 4);
            short8 s0h, s0l;
            #pragma unroll
            for (int jj = 0; jj < 4; ++jj) {
                unsigned short h1 = f2bh(s0a[jj]);
                s0h[jj] = (short)h1; s0l[jj] = (short)f2bh(s0a[jj] - b2f(h1));
                unsigned short h2 = f2bh(s0b[jj]);
                s0h[4 + jj] = (short)h2; s0l[4 + jj] = (short)f2bh(s0b[jj] - b2f(h2));
            }
            acc[ni] = __builtin_amdgcn_mfma_f32_16x16x32_bf16(rh[ks], s0h, acc[ni], 0, 0, 0);
            acc[ni] = __builtin_amdgcn_mfma_f32_16x16x32_bf16(rh[ks], s0l, acc[ni], 0, 0, 0);
            acc[ni] = __builtin_amdgcn_mfma_f32_16x16x32_bf16(rl[ks], s0h, acc[ni], 0, 0, 0);
            if (cc > 0) {
                accC[ni] = __builtin_amdgcn_mfma_f32_16x16x32_bf16(qh[ks], s0h, accC[ni], 0, 0, 0);
                accC[ni] = __builtin_amdgcn_mfma_f32_16x16x32_bf16(qh[ks], s0l, accC[ni], 0, 0, 0);
                accC[ni] = __builtin_amdgcn_mfma_f32_16x16x32_bf16(ql[ks], s0h, accC[ni], 0, 0, 0);
            }
        }
    }

    // ---- SA = SA0 + corr -> global + SAf (LDS, stride 65) ----
    #pragma unroll
    for (int ni = 0; ni < 4; ++ni) {
        #pragma unroll
        for (int r = 0; r < 4; ++r) {
            const int t = 16 * w + kg * 4 + r;
            const int i = ni * 16 + r16;
            const size_t off = base0 + (size_t)t * Cn + i;
            float sa = SAp[off] + accC[ni][r];
            SAp[off] = sa;
            SAf[t * 65 + i] = sa;
        }
    }
    __syncthreads();

    // ---- SA^T staging (column-read / row-write, hi bf16 only) ----
    {
        const int rj = tid & 63, tq = tid >> 6;
        unsigned short tmp[16];
        #pragma unroll
        for (int u = 0; u < 16; ++u)
            tmp[u] = f2bh(SAf[(tq * 16 + u) * 65 + rj]);
        short8 o0, o1;
        #pragma unroll
        for (int u = 0; u < 8; ++u) { o0[u] = (short)tmp[u]; o1[u] = (short)tmp[8 + u]; }
        *(short8*)&sahS[rj * 72 + tq * 16] = o0;
        *(short8*)&sahS[rj * 72 + tq * 16 + 8] = o1;
    }
    __syncthreads();   // SAf dead; scoreS region usable

    // ---- Kr scores (wave-local) + Y2 ----
    #pragma unroll
    for (int si = 0; si < 4; ++si) {
        f32x4 sc2 = (f32x4){0.f, 0.f, 0.f, 0.f};
        #pragma unroll
        for (int ks = 0; ks < 2; ++ks) {
            const int srow = si * 16 + r16;
            const int j0 = ks * 32 + kg * 8;
            short8 kbh = *(const short8*)&khS[srow * 72 + j0];
            short8 kbl = *(const short8*)&klS[srow * 72 + j0];
            sc2 = __builtin_amdgcn_mfma_f32_16x16x32_bf16(rh[ks], kbh, sc2, 0, 0, 0);
            sc2 = __builtin_amdgcn_mfma_f32_16x16x32_bf16(rh[ks], kbl, sc2, 0, 0, 0);
            sc2 = __builtin_amdgcn_mfma_f32_16x16x32_bf16(rl[ks], kbh, sc2, 0, 0, 0);
        }
        const int s = si * 16 + r16;
        #pragma unroll
        for (int r = 0; r < 4; ++r) {
            const int t = 16 * w + kg * 4 + r;
            scoreS[t * 72 + s] = (s <= t) ? f2bh(sc2[r]) : (unsigned short)0;
        }
    }
    #pragma unroll
    for (int ni = 0; ni < 4; ++ni) {
        #pragma unroll
        for (int ks = 0; ks < 2; ++ks) {
            short8 af = *(const short8*)&scoreS[(16 * w + r16) * 72 + ks * 32 + kg * 8];
            short8 vf = *(const short8*)&vtS[(ni * 16 + r16) * 72 + ks * 32 + kg * 8];
            acc[ni] = __builtin_amdgcn_mfma_f32_16x16x32_bf16(af, vf, acc[ni], 0, 0, 0);
        }
    }
    __syncthreads();

    // ---- Mr scores + Y3 (single-bf16 SA) ----
    #pragma unroll
    for (int si = 0; si < 4; ++si) {
        f32x4 sc2 = (f32x4){0.f, 0.f, 0.f, 0.f};
        #pragma unroll
        for (int ks = 0; ks < 2; ++ks) {
            const int srow = si * 16 + r16;
            const int j0 = ks * 32 + kg * 8;
            short8 bbh = *(const short8*)&bhS[srow * 72 + j0];
            short8 bbl = *(const short8*)&blS[srow * 72 + j0];
            sc2 = __builtin_amdgcn_mfma_f32_16x16x32_bf16(rh[ks], bbh, sc2, 0, 0, 0);
            sc2 = __builtin_amdgcn_mfma_f32_16x16x32_bf16(rh[ks], bbl, sc2, 0, 0, 0);
            sc2 = __builtin_amdgcn_mfma_f32_16x16x32_bf16(rl[ks], bbh, sc2, 0, 0, 0);
        }
        const int s = si * 16 + r16;
        #pragma unroll
        for (int r = 0; r < 4; ++r) {
            const int t = 16 * w + kg * 4 + r;
            scoreS[t * 72 + s] = (s <= t) ? f2bh(sc2[r]) : (unsigned short)0;
        }
    }
    #pragma unroll
    for (int ni = 0; ni < 4; ++ni) {
        #pragma unroll
        for (int ks = 0; ks < 2; ++ks) {
            short8 af = *(const short8*)&scoreS[(16 * w + r16) * 72 + ks * 32 + kg * 8];
            short8 sh = *(const short8*)&sahS[(ni * 16 + r16) * 72 + ks * 32 + kg * 8];
            acc[ni] = __builtin_amdgcn_mfma_f32_16x16x32_bf16(af, sh, acc[ni], 0, 0, 0);
        }
    }

    // ---- fused k_elem2: groupnorm + bonus + gate -> AG (bf16) ----
    {
        const int hh = bh & 15;
        float rkv[4], gnwv[4], gnbv[4];
        #pragma unroll
        for (int ni = 0; ni < 4; ++ni) {
            const int c = hh * 64 + ni * 16 + r16;
            rkv[ni] = rk[c]; gnwv[ni] = gnw[c]; gnbv[ni] = gnb[c];
        }
        #pragma unroll
        for (int r = 0; r < 4; ++r) {
            const int t = 16 * w + kg * 4 + r;
            const size_t rowb = base0 + (size_t)t * Cn;
            float s1 = 0.f, s2 = 0.f, p = 0.f;
            float yv[4];
            #pragma unroll
            for (int ni = 0; ni < 4; ++ni) {
                float y = acc[ni][r];
                yv[ni] = y;
                s1 += y; s2 += y * y;
                const int i = ni * 16 + r16;
                p += b2f(Rp[rowb + i]) * b2f(Kp[rowb + i]) * rkv[ni];
            }
            s1 += __shfl_xor(s1, 1, 64); s1 += __shfl_xor(s1, 2, 64);
            s1 += __shfl_xor(s1, 4, 64); s1 += __shfl_xor(s1, 8, 64);
            s2 += __shfl_xor(s2, 1, 64); s2 += __shfl_xor(s2, 2, 64);
            s2 += __shfl_xor(s2, 4, 64); s2 += __shfl_xor(s2, 8, 64);
            p  += __shfl_xor(p, 1, 64);  p  += __shfl_xor(p, 2, 64);
            p  += __shfl_xor(p, 4, 64);  p  += __shfl_xor(p, 8, 64);
            float mean = s1 * (1.f / 64.f);
            float var = s2 * (1.f / 64.f) - mean * mean;
            float rs = rsqrtf(var + 0.00064f);
            #pragma unroll
            for (int ni = 0; ni < 4; ++ni) {
                const int i = ni * 16 + r16;
                float xn = (yv[ni] - mean) * rs * gnwv[ni] + gnbv[ni];
                float vv2 = b2f(vtS[i * 72 + t]);
                float xatt = xn + p * vv2;
                float gv = b2f(Gb[rowb + i]);
                AG[rowb + i] = f2b(xatt * gv);
            }
        }
    }
}

// ---------- MERGED back: Wo GEMM (z=0, bx-owning swz) + layernorm/state_rep (z=1) ----------
__global__ __launch_bounds__(256) void k_back(
    const unsigned short* __restrict__ AG, const unsigned short* __restrict__ WoB,
    float* __restrict__ out_o,
    const float* __restrict__ SAp,
    const float* __restrict__ lnw, const float* __restrict__ lnb,
    const float* __restrict__ vf_in, float* __restrict__ vf_out,
    float* __restrict__ outp)
{
    if (blockIdx.z == 0) {
        int bxs = blockIdx.x, bys = blockIdx.y;
        xcd_swz(bxs, bys);
        gemm_lds_body<0, 1>(AG, Cn, WoB, Cn, out_o, nullptr, Cn, nullptr, Cn,
                            bxs * 128, bys * 128);
        return;
    }
    __shared__ float red1[4], red2[4];
    const int tid = threadIdx.x;
    const int fb = blockIdx.y * 32 + blockIdx.x;   // 0..255
    for (int rr = 0; rr < 16; ++rr) {
        size_t row = (size_t)fb * 16 + rr;
        *(f32x4*)(vf_out + row * Cn + tid * 4) = *(const f32x4*)(vf_in + row * Cn + tid * 4);

        f32x4 v = *(const f32x4*)(SAp + row * Cn + tid * 4);
        float s1 = v[0] + v[1] + v[2] + v[3];
        float s2 = v[0] * v[0] + v[1] * v[1] + v[2] * v[2] + v[3] * v[3];
        #pragma unroll
        for (int m = 1; m < 64; m <<= 1) {
            s1 += __shfl_xor(s1, m, 64);
            s2 += __shfl_xor(s2, m, 64);
        }
        if ((tid & 63) == 0) { red1[tid >> 6] = s1; red2[tid >> 6] = s2; }
        __syncthreads();
        s1 = red1[0] + red1[1] + red1[2] + red1[3];
        s2 = red2[0] + red2[1] + red2[2] + red2[3];
        float mean = s1 * (1.f / 1024.f);
        float var = s2 * (1.f / 1024.f) - mean * mean;
        float rs = rsqrtf(var + 1e-5f);
        f32x4 o;
        #pragma unroll
        for (int u = 0; u < 4; ++u) {
            int c = tid * 4 + u;
            o[u] = (v[u] - mean) * rs * lnw[c] + lnb[c];
        }
        *(f32x4*)(outp + row * Cn + tid * 4) = o;
        __syncthreads();   // red1/red2 reuse next iteration
    }
}

// ---------- launcher ----------
extern "C" void kernel_launch(void* const* d_in, const int* in_sizes, int n_in,
                              void* d_out, int out_size, void* d_ws, size_t ws_size,
                              hipStream_t stream)
{
    (void)in_sizes; (void)n_in; (void)out_size; (void)ws_size;
    const float* x      = (const float*)d_in[0];
    const float* vfirst = (const float*)d_in[1];
    const float* x_r    = (const float*)d_in[2];
    const float* x_w    = (const float*)d_in[3];
    const float* x_k    = (const float*)d_in[4];
    const float* x_v    = (const float*)d_in[5];
    const float* x_a    = (const float*)d_in[6];
    const float* x_g    = (const float*)d_in[7];
    const float* w0     = (const float*)d_in[8];
    const float* w1     = (const float*)d_in[9];
    const float* w2     = (const float*)d_in[10];
    const float* a0     = (const float*)d_in[11];
    const float* a1     = (const float*)d_in[12];
    const float* a2     = (const float*)d_in[13];
    const float* v0     = (const float*)d_in[14];
    const float* v1     = (const float*)d_in[15];
    const float* v2     = (const float*)d_in[16];
    const float* g1     = (const float*)d_in[17];
    const float* g2     = (const float*)d_in[18];
    const float* k_k    = (const float*)d_in[19];
    const float* k_a    = (const float*)d_in[20];
    const float* r_k    = (const float*)d_in[21];
    const float* Wr     = (const float*)d_in[22];
    const float* Wk     = (const float*)d_in[23];
    const float* Wv     = (const float*)d_in[24];
    const float* Wo     = (const float*)d_in[25];
    const float* gn_w   = (const float*)d_in[26];
    const float* gn_b   = (const float*)d_in[27];
    const float* ln_w   = (const float*)d_in[28];
    const float* ln_b   = (const float*)d_in[29];

    char* ws = (char*)d_ws;
    size_t off = 0;
    auto alloc = [&](size_t bytes) -> void* {
        void* p = ws + off;
        off += (bytes + 255) & ~(size_t)255;
        return p;
    };
    unsigned short* Rb  = (unsigned short*)alloc(MX * 2);  // raw r; reused as AG
    unsigned short* Kb  = (unsigned short*)alloc(MX * 2);  // raw k -> k_final
    unsigned short* Vb  = (unsigned short*)alloc(MX * 2);  // raw v -> v_final
    unsigned short* SVb = (unsigned short*)alloc(MX * 2);  // sigmoid(v-gate)
    unsigned short* Ab  = (unsigned short*)alloc(MX * 2);  // sigmoid(a) -> bb
    unsigned short* Gb  = (unsigned short*)alloc(MX * 2);  // g
    float* Wdec = (float*)alloc(MX * 4);                   // decay (f32)
    float* Cg   = (float*)alloc(MX * 4);                   // chunk offsets Z
    float* Pg   = (float*)alloc(MX * 4);                   // chunk transfer mats (P^T)
    float* Qg   = (float*)alloc(MX * 4);                   // q_t vectors
    unsigned short* hw = (unsigned short*)alloc((size_t)Mrows * 64 * 2);
    unsigned short* ha = (unsigned short*)alloc((size_t)Mrows * 64 * 2);
    unsigned short* hv = (unsigned short*)alloc((size_t)Mrows * 64 * 2);
    unsigned short* hg = (unsigned short*)alloc((size_t)Mrows * 160 * 2);
    unsigned short* WrB = (unsigned short*)alloc(1048576 * 2);
    unsigned short* WkB = (unsigned short*)alloc(1048576 * 2);
    unsigned short* WvB = (unsigned short*)alloc(1048576 * 2);
    unsigned short* WoB = (unsigned short*)alloc(1048576 * 2);
    unsigned short* w1T = (unsigned short*)alloc(65536 * 2);
    unsigned short* w2T = (unsigned short*)alloc(65536 * 2);
    unsigned short* a1T = (unsigned short*)alloc(65536 * 2);
    unsigned short* a2T = (unsigned short*)alloc(65536 * 2);
    unsigned short* v1T = (unsigned short*)alloc(65536 * 2);
    unsigned short* v2T = (unsigned short*)alloc(65536 * 2);
    unsigned short* g1T = (unsigned short*)alloc(163840 * 2);
    unsigned short* g2T = (unsigned short*)alloc(163840 * 2);

    // premix buffers alias later-written regions (dead before those writes):
    unsigned short* xrB = (unsigned short*)Cg;
    unsigned short* xkB = (unsigned short*)Cg + MX;
    unsigned short* xvB = (unsigned short*)Wdec;
    unsigned short* xgB = (unsigned short*)Wdec + MX;
    unsigned short* xwB = Ab;
    unsigned short* xaB = Gb;

    float* out_o  = (float*)d_out;
    float* out_vf = out_o + MX;
    float* out_sr = out_o + 2 * MX;
    float* Sinit = out_vf;                  // chunk-initial states (dead after kY)
    float* SAb   = out_sr;                  // sa0 -> corrected by kY (LN'd in place)
    unsigned short* AG = Rb;                // kY writes AG directly

    k_prep_all<<<dim3(8960), 256, 0, stream>>>(
        x, x_r, x_w, x_k, x_v, x_a, x_g,
        xrB, xwB, xkB, xvB, xaB, xgB,
        Wr, Wk, Wv, Wo, WrB, WkB, WvB, WoB,
        w1, w2, a1, a2, v1, v2, g1, g2,
        w1T, w2T, a1T, a2T, v1T, v2T, g1T, g2T);

    // merged compact front: small1 (96 blocks, first) + R/K/V (768 blocks)
    gemm_front<<<dim3(864), 256, 0, stream>>>(
        xrB, xkB, xvB, WrB, WkB, WvB, Rb, Kb, Vb,
        xwB, xaB, xgB, w1T, a1T, v1T, g1T,
        hw, ha, hv, hg);

    gemm_s2<<<dim3(32, 8, 4), 256, 0, stream>>>(hw, ha, hv, hg,
                                                w2T, a2T, v2T, g2T,
                                                Wdec, Ab, SVb, Gb,
                                                w0, a0, v0);

    // chunked scan: A (WY form, 1024 thr), B (combine), Y (MFMA + elem2 fused)
    kA_wy<<<dim3(1024), 1024, 0, stream>>>(Wdec, Kb, Vb, SVb, Ab,
                                           vfirst, k_k, k_a,
                                           Pg, Cg, Qg, SAb);
    kB_combine<<<dim3(64), 256, 0, stream>>>(Pg, Cg, Sinit);
    kY_mfma<<<dim3(1024), 256, 0, stream>>>(Wdec, Rb, Kb, Ab, Vb, Gb,
                                            Qg, Sinit, gn_w, gn_b, r_k,
                                            SAb, AG);

    // merged: Wo GEMM (z=0) + layernorm/state_rep + v_first copy (z=1)
    k_back<<<dim3(32, 8, 2), 256, 0, stream>>>(AG, WoB, out_o,
                                               SAb, ln_w, ln_b,
                                               vfirst, out_vf, out_sr);
}